// Round 6
// baseline (204.177 us; speedup 1.0000x reference)
//
#include <hip/hip_runtime.h>
#include <stdint.h>

#define B_ 32
#define S_ 512
#define D_ 768
#define H_ 12
#define DH_ 64

typedef __attribute__((ext_vector_type(8))) short bf16x8;
typedef __attribute__((ext_vector_type(4))) float f32x4;
typedef __attribute__((ext_vector_type(4))) short short4v;

// ---- LDS layout (u16 units), pitch 72 => conflict-free b128 fragment reads.
// Wkl [64][72] @ 0       Wk bf16
// Wvl [64][72] @ 4608    Wv bf16
// xs  [64][72] @ 9216    x chunk
// Kc  [64][72] @ 13824   K chunk (sigma-permuted e-cols); Wq staging in pre-phase
// Vt  [64][72] @ 18432   V^T chunk (sigma-permuted t-cols)
#define WP 72
#define WK_U 0
#define WV_U 4608
#define XS_U 9216
#define KC_U 13824
#define VT_U 18432
#define SMEM_BYTES 46080  // 3 blocks/CU

__device__ __forceinline__ unsigned short f2bf(float f) {
  uint32_t u = __builtin_bit_cast(uint32_t, f);
  return (unsigned short)((u + 0x7fffu + ((u >> 16) & 1u)) >> 16);  // RNE
}

// sigma: value index v = 16*tile + r16 -> stored col so a contiguous 8-elem
// read at col8 = 32c + 8g yields k-order 32c + 16*(j>>2) + 4g + (j&3).
__device__ __forceinline__ int sigma(int tile, int r16) {
  return 32 * (tile >> 1) + 8 * (r16 >> 2) + 4 * (tile & 1) + (r16 & 3);
}

__device__ __forceinline__ bf16x8 ldfrag8(const unsigned short* p) {
  return *(const bf16x8*)p;  // single ds_read_b128
}

#define MFMA(a, b, c) __builtin_amdgcn_mfma_f32_16x16x32_bf16((a), (b), (c), 0, 0, 0)

extern "C" __global__ void __launch_bounds__(256, 3)
mhsa_mfma(const float* __restrict__ seq, const float* __restrict__ Wq,
          const float* __restrict__ Wk, const float* __restrict__ Wv,
          const float* __restrict__ bq, const float* __restrict__ bk,
          const float* __restrict__ bv, float* __restrict__ out)
{
  extern __shared__ unsigned short lds[];
  unsigned short* Wkl = lds + WK_U;
  unsigned short* Wvl = lds + WV_U;
  unsigned short* xs  = lds + XS_U;
  unsigned short* Kc  = lds + KC_U;
  unsigned short* Vt  = lds + VT_U;

  const int tid = threadIdx.x;
  const int lane = tid & 63;
  const int w = tid >> 6;       // wave 0..3
  const int g = lane >> 4;      // lane quad-group 0..3
  const int r16 = lane & 15;
  const int cb8 = 8 * g;        // contiguous fragment column base
  const int bh = blockIdx.x;
  const int b = bh / H_;
  const int h = bh - b * H_;
  const int r0 = blockIdx.y * 256;  // this block's q-row base

  const float* seqh = seq + (size_t)b * (S_ * D_) + h * DH_;

  // ---- stage Wk, Wv, Wq(into Kc) fp32 -> bf16 LDS ----
  #pragma unroll
  for (int i = 0; i < 4; ++i) {
    int fidx = tid + i * 256;            // 1024 float4 groups per matrix
    int row = fidx >> 4, c4 = (fidx & 15) << 2;
    {
      const float4 v = *(const float4*)(Wk + h * 4096 + row * 64 + c4);
      short4v s = {(short)f2bf(v.x), (short)f2bf(v.y), (short)f2bf(v.z), (short)f2bf(v.w)};
      *(short4v*)(Wkl + row * WP + c4) = s;
    }
    {
      const float4 v = *(const float4*)(Wv + h * 4096 + row * 64 + c4);
      short4v s = {(short)f2bf(v.x), (short)f2bf(v.y), (short)f2bf(v.z), (short)f2bf(v.w)};
      *(short4v*)(Wvl + row * WP + c4) = s;
    }
    {
      const float4 v = *(const float4*)(Wq + h * 4096 + row * 64 + c4);
      short4v s = {(short)f2bf(v.x), (short)f2bf(v.y), (short)f2bf(v.z), (short)f2bf(v.w)};
      *(short4v*)(Kc + row * WP + c4) = s;
    }
  }

  float bk_l[4], bv_l[4];
  #pragma unroll
  for (int e4 = 0; e4 < 4; ++e4) bk_l[e4] = bk[h * 64 + 16 * e4 + r16];
  #pragma unroll
  for (int rr = 0; rr < 4; ++rr) bv_l[rr] = bv[h * 64 + 16 * w + 4 * g + rr];
  __syncthreads();

  // ---- persistent Wv A-fragments (e-tile = w) ----
  bf16x8 wvA[2];
  #pragma unroll
  for (int ec = 0; ec < 2; ++ec)
    wvA[ec] = ldfrag8(Wvl + (16 * w + r16) * WP + 32 * ec + cb8);

  // ---- pre-phase: Q^T via MFMA -> qB register fragments (Wq lives in Kc) ----
  bf16x8 qB[4][2];  // [m-tile][e-chunk]; elem j: e = 32ec+16(j>>2)+4g+(j&3)
  for (int cq = 0; cq < 4; ++cq) {
    #pragma unroll
    for (int i = 0; i < 4; ++i) {
      int fidx = tid + i * 256;
      int row = fidx >> 4, c4 = (fidx & 15) << 2;
      const float4 xv = *(const float4*)(seqh + (size_t)(r0 + cq * 64 + row) * D_ + c4);
      short4v s = {(short)f2bf(xv.x), (short)f2bf(xv.y), (short)f2bf(xv.z), (short)f2bf(xv.w)};
      *(short4v*)(xs + row * WP + c4) = s;
    }
    __syncthreads();
    if (w == cq) {
      #pragma unroll
      for (int mt = 0; mt < 4; ++mt) {
        bf16x8 xB[2];
        #pragma unroll
        for (int ec = 0; ec < 2; ++ec)
          xB[ec] = ldfrag8(xs + (16 * mt + r16) * WP + 32 * ec + cb8);
        f32x4 qt[4];
        #pragma unroll
        for (int e4 = 0; e4 < 4; ++e4) {
          f32x4 acc = {0.f, 0.f, 0.f, 0.f};
          #pragma unroll
          for (int ec = 0; ec < 2; ++ec)
            acc = MFMA(ldfrag8(Kc + (16 * e4 + r16) * WP + 32 * ec + cb8), xB[ec], acc);
          qt[e4] = acc;
        }
        #pragma unroll
        for (int ec2 = 0; ec2 < 2; ++ec2) {
          bf16x8 f;
          #pragma unroll
          for (int j = 0; j < 8; ++j) {
            int e4 = 2 * ec2 + (j >> 2), rr = j & 3;
            f[j] = (short)f2bf(qt[e4][rr] + bq[h * 64 + 16 * e4 + 4 * g + rr]);
          }
          qB[mt][ec2] = f;
        }
      }
    }
    __syncthreads();
  }

  // ---- main flash loop over 8 t-chunks of 64 ----
  f32x4 O[4][4];
  #pragma unroll
  for (int mt = 0; mt < 4; ++mt)
    #pragma unroll
    for (int e4 = 0; e4 < 4; ++e4) O[mt][e4] = {0.f, 0.f, 0.f, 0.f};
  float m_st[4] = {-1e30f, -1e30f, -1e30f, -1e30f};
  float l_st[4] = {0.f, 0.f, 0.f, 0.f};

  for (int c = 0; c < 8; ++c) {
    #pragma unroll
    for (int i = 0; i < 4; ++i) {
      int fidx = tid + i * 256;
      int row = fidx >> 4, c4 = (fidx & 15) << 2;
      const float4 xv = *(const float4*)(seqh + (size_t)(c * 64 + row) * D_ + c4);
      short4v s = {(short)f2bf(xv.x), (short)f2bf(xv.y), (short)f2bf(xv.z), (short)f2bf(xv.w)};
      *(short4v*)(xs + row * WP + c4) = s;
    }
    __syncthreads();  // barrier A: staging done AND prev chunk's Kc/Vt reads done

    // K-proj: wave w owns t-tile w (16 rows); e-cols sigma-permuted
    {
      bf16x8 aX[2];
      #pragma unroll
      for (int ec = 0; ec < 2; ++ec)
        aX[ec] = ldfrag8(xs + (w * 16 + r16) * WP + 32 * ec + cb8);
      #pragma unroll
      for (int e4 = 0; e4 < 4; ++e4) {
        f32x4 acc = {0.f, 0.f, 0.f, 0.f};
        #pragma unroll
        for (int ec = 0; ec < 2; ++ec)
          acc = MFMA(aX[ec], ldfrag8(Wkl + (16 * e4 + r16) * WP + 32 * ec + cb8), acc);
        const float bkv = bk_l[e4];
        const int rb = w * 16 + 4 * g;
        const int cs = sigma(e4, r16);
        Kc[(rb + 0) * WP + cs] = f2bf(acc[0] + bkv);
        Kc[(rb + 1) * WP + cs] = f2bf(acc[1] + bkv);
        Kc[(rb + 2) * WP + cs] = f2bf(acc[2] + bkv);
        Kc[(rb + 3) * WP + cs] = f2bf(acc[3] + bkv);
      }
    }
    // V^T-proj: wave w owns e-tile w, all 4 t-tiles; t-cols sigma-permuted
    #pragma unroll
    for (int tt = 0; tt < 4; ++tt) {
      bf16x8 xB[2];
      #pragma unroll
      for (int ec = 0; ec < 2; ++ec)
        xB[ec] = ldfrag8(xs + (tt * 16 + r16) * WP + 32 * ec + cb8);
      f32x4 acc = {0.f, 0.f, 0.f, 0.f};
      #pragma unroll
      for (int ec = 0; ec < 2; ++ec) acc = MFMA(wvA[ec], xB[ec], acc);
      const int rb = 16 * w + 4 * g;
      const int cs = sigma(tt, r16);
      Vt[(rb + 0) * WP + cs] = f2bf(acc[0] + bv_l[0]);
      Vt[(rb + 1) * WP + cs] = f2bf(acc[1] + bv_l[1]);
      Vt[(rb + 2) * WP + cs] = f2bf(acc[2] + bv_l[2]);
      Vt[(rb + 3) * WP + cs] = f2bf(acc[3] + bv_l[3]);
    }
    __syncthreads();  // barrier B: Kc/Vt ready

    // per m-tile: S^T + online softmax + PV
    #pragma unroll
    for (int mt = 0; mt < 4; ++mt) {
      f32x4 st[4];
      #pragma unroll
      for (int tt = 0; tt < 4; ++tt) {
        bf16x8 aK[2];
        #pragma unroll
        for (int ec = 0; ec < 2; ++ec)
          aK[ec] = ldfrag8(Kc + (tt * 16 + r16) * WP + 32 * ec + cb8);
        f32x4 acc = {0.f, 0.f, 0.f, 0.f};
        #pragma unroll
        for (int ec = 0; ec < 2; ++ec) acc = MFMA(aK[ec], qB[mt][ec], acc);
        st[tt] = acc;
      }
      float mx = st[0][0];
      #pragma unroll
      for (int tt = 0; tt < 4; ++tt)
        #pragma unroll
        for (int rr = 0; rr < 4; ++rr) mx = fmaxf(mx, st[tt][rr]);
      mx = fmaxf(mx, __shfl_xor(mx, 16, 64));
      mx = fmaxf(mx, __shfl_xor(mx, 32, 64));
      float mn = fmaxf(m_st[mt], mx);
      float al = __expf(m_st[mt] - mn);
      m_st[mt] = mn;
      float sum = 0.f;
      #pragma unroll
      for (int tt = 0; tt < 4; ++tt)
        #pragma unroll
        for (int rr = 0; rr < 4; ++rr) {
          float pv = __expf(st[tt][rr] - mn);
          st[tt][rr] = pv;
          sum += pv;
        }
      sum += __shfl_xor(sum, 16, 64);
      sum += __shfl_xor(sum, 32, 64);
      l_st[mt] = l_st[mt] * al + sum;
      float af[4];
      #pragma unroll
      for (int rr = 0; rr < 4; ++rr) af[rr] = __shfl(al, 4 * g + rr, 64);
      #pragma unroll
      for (int e4 = 0; e4 < 4; ++e4)
        #pragma unroll
        for (int rr = 0; rr < 4; ++rr) O[mt][e4][rr] *= af[rr];
      #pragma unroll
      for (int u = 0; u < 2; ++u) {
        bf16x8 f;
        #pragma unroll
        for (int j = 0; j < 8; ++j) f[j] = (short)f2bf(st[2 * u + (j >> 2)][j & 3]);
        #pragma unroll
        for (int e4 = 0; e4 < 4; ++e4) {
          bf16x8 vB = ldfrag8(Vt + (16 * e4 + r16) * WP + 32 * u + cb8);
          O[mt][e4] = MFMA(f, vB, O[mt][e4]);
        }
      }
    }
  }

  // ---- epilogue: normalize + store ----
  #pragma unroll
  for (int mt = 0; mt < 4; ++mt) {
    float inv[4];
    #pragma unroll
    for (int rr = 0; rr < 4; ++rr) inv[rr] = 1.0f / __shfl(l_st[mt], 4 * g + rr, 64);
    #pragma unroll
    for (int e4 = 0; e4 < 4; ++e4)
      #pragma unroll
      for (int rr = 0; rr < 4; ++rr)
        out[(size_t)(b * S_ + r0 + w * 64 + 16 * mt + 4 * g + rr) * D_ + h * DH_ + 16 * e4 + r16] =
            O[mt][e4][rr] * inv[rr];
  }
}

extern "C" void kernel_launch(void* const* d_in, const int* in_sizes, int n_in,
                              void* d_out, int out_size, void* d_ws, size_t ws_size,
                              hipStream_t stream) {
  const float* seq = (const float*)d_in[0];
  const float* Wq  = (const float*)d_in[1];
  const float* Wk  = (const float*)d_in[2];
  const float* Wv  = (const float*)d_in[3];
  const float* bq  = (const float*)d_in[4];
  const float* bk  = (const float*)d_in[5];
  const float* bv  = (const float*)d_in[6];
  float* outp = (float*)d_out;

  hipFuncSetAttribute((const void*)mhsa_mfma,
                      hipFuncAttributeMaxDynamicSharedMemorySize, SMEM_BYTES);
  dim3 grid(B_ * H_, 2);
  mhsa_mfma<<<grid, 256, SMEM_BYTES, stream>>>(seq, Wq, Wk, Wv, bq, bk, bv, outp);
}

// Round 7
// 118.406 us; speedup vs baseline: 1.7244x; 1.7244x over previous
//
#include <hip/hip_runtime.h>
#include <stdint.h>

#define B_ 32
#define S_ 512
#define D_ 768
#define H_ 12
#define DH_ 64

typedef __attribute__((ext_vector_type(8))) short bf16x8;
typedef __attribute__((ext_vector_type(4))) float f32x4;
typedef __attribute__((ext_vector_type(4))) short short4v;

// ---- LDS layout (u16 units), pitch 72 => conflict-free b128 fragment reads.
// Wkl [64][72] @ 0      Wk bf16 (persistent)
// xs  [64][72] @ 4608   x chunk
// Kc  [64][72] @ 9216   K chunk (sigma-permuted e-cols); Wq staging in prologue
// Vt  [64][72] @ 13824  V^T chunk (sigma-permuted t-cols); Wv staging in prologue
#define WP 72
#define WK_U 0
#define XS_U 4608
#define KC_U 9216
#define VT_U 13824
#define SMEM_BYTES 36864  // 4 blocks/CU by LDS

__device__ __forceinline__ unsigned short f2bf(float f) {
  uint32_t u = __builtin_bit_cast(uint32_t, f);
  return (unsigned short)((u + 0x7fffu + ((u >> 16) & 1u)) >> 16);  // RNE
}

// sigma: value index v = 16*tile + r16 -> stored col so a contiguous 8-elem
// read at col8 = 32c + 8g yields k-order 32c + 16*(j>>2) + 4g + (j&3).
__device__ __forceinline__ int sigma(int tile, int r16) {
  return 32 * (tile >> 1) + 8 * (r16 >> 2) + 4 * (tile & 1) + (r16 & 3);
}

__device__ __forceinline__ bf16x8 ldfrag8(const unsigned short* p) {
  return *(const bf16x8*)p;  // single ds_read_b128
}

#define MFMA(a, b, c) __builtin_amdgcn_mfma_f32_16x16x32_bf16((a), (b), (c), 0, 0, 0)

extern "C" __global__ void __launch_bounds__(256, 4)
mhsa_mfma(const float* __restrict__ seq, const float* __restrict__ Wq,
          const float* __restrict__ Wk, const float* __restrict__ Wv,
          const float* __restrict__ bq, const float* __restrict__ bk,
          const float* __restrict__ bv, float* __restrict__ out)
{
  extern __shared__ unsigned short lds[];
  unsigned short* Wkl = lds + WK_U;
  unsigned short* xs  = lds + XS_U;
  unsigned short* Kc  = lds + KC_U;
  unsigned short* Vt  = lds + VT_U;

  const int tid = threadIdx.x;
  const int lane = tid & 63;
  const int w = tid >> 6;       // wave 0..3
  const int g = lane >> 4;      // lane quad-group 0..3
  const int r16 = lane & 15;
  const int cb8 = 8 * g;        // contiguous fragment column base
  const int bh = blockIdx.x;
  const int b = bh / H_;
  const int h = bh - b * H_;
  const int r0 = blockIdx.y * 128;  // this block's q-row base (128 rows)

  const float* seqh = seq + (size_t)b * (S_ * D_) + h * DH_;

  // ---- stage Wk(->Wkl), Wq(->Kc), Wv(->Vt) fp32 -> bf16 LDS ----
  #pragma unroll
  for (int i = 0; i < 4; ++i) {
    int fidx = tid + i * 256;            // 1024 float4 groups per matrix
    int row = fidx >> 4, c4 = (fidx & 15) << 2;
    {
      const float4 v = *(const float4*)(Wk + h * 4096 + row * 64 + c4);
      short4v s = {(short)f2bf(v.x), (short)f2bf(v.y), (short)f2bf(v.z), (short)f2bf(v.w)};
      *(short4v*)(Wkl + row * WP + c4) = s;
    }
    {
      const float4 v = *(const float4*)(Wq + h * 4096 + row * 64 + c4);
      short4v s = {(short)f2bf(v.x), (short)f2bf(v.y), (short)f2bf(v.z), (short)f2bf(v.w)};
      *(short4v*)(Kc + row * WP + c4) = s;
    }
    {
      const float4 v = *(const float4*)(Wv + h * 4096 + row * 64 + c4);
      short4v s = {(short)f2bf(v.x), (short)f2bf(v.y), (short)f2bf(v.z), (short)f2bf(v.w)};
      *(short4v*)(Vt + row * WP + c4) = s;
    }
  }

  float bk_l[4], bv_l[4];
  #pragma unroll
  for (int e4 = 0; e4 < 4; ++e4) bk_l[e4] = bk[h * 64 + 16 * e4 + r16];
  #pragma unroll
  for (int rr = 0; rr < 4; ++rr) bv_l[rr] = bv[h * 64 + 16 * w + 4 * g + rr];
  __syncthreads();

  // ---- persistent Wv A-fragments (e-tile = w); Wv staged in Vt ----
  bf16x8 wvA[2];
  #pragma unroll
  for (int ec = 0; ec < 2; ++ec)
    wvA[ec] = ldfrag8(Vt + (16 * w + r16) * WP + 32 * ec + cb8);

  // ---- pre-phase: Q^T via MFMA -> qB register fragments (Wq lives in Kc) ----
  // Block covers 128 q-rows = 2 chunks of 64; wave w owns rows 32*w..32*w+31.
  bf16x8 qB[2][2];  // [m-tile][e-chunk]; elem j: e = 32ec+16(j>>2)+4g+(j&3)
  for (int cq = 0; cq < 2; ++cq) {
    #pragma unroll
    for (int i = 0; i < 4; ++i) {
      int fidx = tid + i * 256;
      int row = fidx >> 4, c4 = (fidx & 15) << 2;
      const float4 xv = *(const float4*)(seqh + (size_t)(r0 + cq * 64 + row) * D_ + c4);
      short4v s = {(short)f2bf(xv.x), (short)f2bf(xv.y), (short)f2bf(xv.z), (short)f2bf(xv.w)};
      *(short4v*)(xs + row * WP + c4) = s;
    }
    __syncthreads();
    if ((w >> 1) == cq) {
      const int lr = 32 * (w & 1);  // wave's rows within this 64-chunk
      #pragma unroll
      for (int mt = 0; mt < 2; ++mt) {
        bf16x8 xB[2];
        #pragma unroll
        for (int ec = 0; ec < 2; ++ec)
          xB[ec] = ldfrag8(xs + (lr + 16 * mt + r16) * WP + 32 * ec + cb8);
        f32x4 qt[4];
        #pragma unroll
        for (int e4 = 0; e4 < 4; ++e4) {
          f32x4 acc = {0.f, 0.f, 0.f, 0.f};
          #pragma unroll
          for (int ec = 0; ec < 2; ++ec)
            acc = MFMA(ldfrag8(Kc + (16 * e4 + r16) * WP + 32 * ec + cb8), xB[ec], acc);
          qt[e4] = acc;
        }
        #pragma unroll
        for (int ec2 = 0; ec2 < 2; ++ec2) {
          bf16x8 f;
          #pragma unroll
          for (int j = 0; j < 8; ++j) {
            int e4 = 2 * ec2 + (j >> 2), rr = j & 3;
            f[j] = (short)f2bf(qt[e4][rr] + bq[h * 64 + 16 * e4 + 4 * g + rr]);
          }
          qB[mt][ec2] = f;
        }
      }
    }
    __syncthreads();
  }

  // ---- main flash loop over 8 t-chunks of 64 ----
  f32x4 O[2][4];
  #pragma unroll
  for (int mt = 0; mt < 2; ++mt)
    #pragma unroll
    for (int e4 = 0; e4 < 4; ++e4) O[mt][e4] = {0.f, 0.f, 0.f, 0.f};
  float m_st[2] = {-1e30f, -1e30f};
  float l_st[2] = {0.f, 0.f};

  for (int c = 0; c < 8; ++c) {
    #pragma unroll
    for (int i = 0; i < 4; ++i) {
      int fidx = tid + i * 256;
      int row = fidx >> 4, c4 = (fidx & 15) << 2;
      const float4 xv = *(const float4*)(seqh + (size_t)(c * 64 + row) * D_ + c4);
      short4v s = {(short)f2bf(xv.x), (short)f2bf(xv.y), (short)f2bf(xv.z), (short)f2bf(xv.w)};
      *(short4v*)(xs + row * WP + c4) = s;
    }
    __syncthreads();  // barrier A: staging done AND prev chunk's Kc/Vt reads done

    // K-proj: wave w owns t-tile w (16 rows); e-cols sigma-permuted
    {
      bf16x8 aX[2];
      #pragma unroll
      for (int ec = 0; ec < 2; ++ec)
        aX[ec] = ldfrag8(xs + (w * 16 + r16) * WP + 32 * ec + cb8);
      #pragma unroll
      for (int e4 = 0; e4 < 4; ++e4) {
        f32x4 acc = {0.f, 0.f, 0.f, 0.f};
        #pragma unroll
        for (int ec = 0; ec < 2; ++ec)
          acc = MFMA(aX[ec], ldfrag8(Wkl + (16 * e4 + r16) * WP + 32 * ec + cb8), acc);
        const float bkv = bk_l[e4];
        const int rb = w * 16 + 4 * g;
        const int cs = sigma(e4, r16);
        Kc[(rb + 0) * WP + cs] = f2bf(acc[0] + bkv);
        Kc[(rb + 1) * WP + cs] = f2bf(acc[1] + bkv);
        Kc[(rb + 2) * WP + cs] = f2bf(acc[2] + bkv);
        Kc[(rb + 3) * WP + cs] = f2bf(acc[3] + bkv);
      }
    }
    // V^T-proj: wave w owns e-tile w, all 4 t-tiles; t-cols sigma-permuted
    #pragma unroll
    for (int tt = 0; tt < 4; ++tt) {
      bf16x8 xB[2];
      #pragma unroll
      for (int ec = 0; ec < 2; ++ec)
        xB[ec] = ldfrag8(xs + (tt * 16 + r16) * WP + 32 * ec + cb8);
      f32x4 acc = {0.f, 0.f, 0.f, 0.f};
      #pragma unroll
      for (int ec = 0; ec < 2; ++ec) acc = MFMA(wvA[ec], xB[ec], acc);
      const int rb = 16 * w + 4 * g;
      const int cs = sigma(tt, r16);
      Vt[(rb + 0) * WP + cs] = f2bf(acc[0] + bv_l[0]);
      Vt[(rb + 1) * WP + cs] = f2bf(acc[1] + bv_l[1]);
      Vt[(rb + 2) * WP + cs] = f2bf(acc[2] + bv_l[2]);
      Vt[(rb + 3) * WP + cs] = f2bf(acc[3] + bv_l[3]);
    }
    __syncthreads();  // barrier B: Kc/Vt ready

    // per m-tile: S^T + online softmax + PV
    #pragma unroll
    for (int mt = 0; mt < 2; ++mt) {
      f32x4 st[4];
      #pragma unroll
      for (int tt = 0; tt < 4; ++tt) {
        bf16x8 aK[2];
        #pragma unroll
        for (int ec = 0; ec < 2; ++ec)
          aK[ec] = ldfrag8(Kc + (tt * 16 + r16) * WP + 32 * ec + cb8);
        f32x4 acc = {0.f, 0.f, 0.f, 0.f};
        #pragma unroll
        for (int ec = 0; ec < 2; ++ec) acc = MFMA(aK[ec], qB[mt][ec], acc);
        st[tt] = acc;
      }
      float mx = st[0][0];
      #pragma unroll
      for (int tt = 0; tt < 4; ++tt)
        #pragma unroll
        for (int rr = 0; rr < 4; ++rr) mx = fmaxf(mx, st[tt][rr]);
      mx = fmaxf(mx, __shfl_xor(mx, 16, 64));
      mx = fmaxf(mx, __shfl_xor(mx, 32, 64));
      float mn = fmaxf(m_st[mt], mx);
      float al = __expf(m_st[mt] - mn);
      m_st[mt] = mn;
      float sum = 0.f;
      #pragma unroll
      for (int tt = 0; tt < 4; ++tt)
        #pragma unroll
        for (int rr = 0; rr < 4; ++rr) {
          float pv = __expf(st[tt][rr] - mn);
          st[tt][rr] = pv;
          sum += pv;
        }
      sum += __shfl_xor(sum, 16, 64);
      sum += __shfl_xor(sum, 32, 64);
      l_st[mt] = l_st[mt] * al + sum;
      float af[4];
      #pragma unroll
      for (int rr = 0; rr < 4; ++rr) af[rr] = __shfl(al, 4 * g + rr, 64);
      #pragma unroll
      for (int e4 = 0; e4 < 4; ++e4)
        #pragma unroll
        for (int rr = 0; rr < 4; ++rr) O[mt][e4][rr] *= af[rr];
      #pragma unroll
      for (int u = 0; u < 2; ++u) {
        bf16x8 f;
        #pragma unroll
        for (int j = 0; j < 8; ++j) f[j] = (short)f2bf(st[2 * u + (j >> 2)][j & 3]);
        #pragma unroll
        for (int e4 = 0; e4 < 4; ++e4) {
          bf16x8 vB = ldfrag8(Vt + (16 * e4 + r16) * WP + 32 * u + cb8);
          O[mt][e4] = MFMA(f, vB, O[mt][e4]);
        }
      }
    }
  }

  // ---- epilogue: normalize + store ----
  #pragma unroll
  for (int mt = 0; mt < 2; ++mt) {
    float inv[4];
    #pragma unroll
    for (int rr = 0; rr < 4; ++rr) inv[rr] = 1.0f / __shfl(l_st[mt], 4 * g + rr, 64);
    #pragma unroll
    for (int e4 = 0; e4 < 4; ++e4)
      #pragma unroll
      for (int rr = 0; rr < 4; ++rr)
        out[(size_t)(b * S_ + r0 + w * 32 + 16 * mt + 4 * g + rr) * D_ + h * DH_ + 16 * e4 + r16] =
            O[mt][e4][rr] * inv[rr];
  }
}

extern "C" void kernel_launch(void* const* d_in, const int* in_sizes, int n_in,
                              void* d_out, int out_size, void* d_ws, size_t ws_size,
                              hipStream_t stream) {
  const float* seq = (const float*)d_in[0];
  const float* Wq  = (const float*)d_in[1];
  const float* Wk  = (const float*)d_in[2];
  const float* Wv  = (const float*)d_in[3];
  const float* bq  = (const float*)d_in[4];
  const float* bk  = (const float*)d_in[5];
  const float* bv  = (const float*)d_in[6];
  float* outp = (float*)d_out;

  hipFuncSetAttribute((const void*)mhsa_mfma,
                      hipFuncAttributeMaxDynamicSharedMemorySize, SMEM_BYTES);
  dim3 grid(B_ * H_, 4);
  mhsa_mfma<<<grid, 256, SMEM_BYTES, stream>>>(seq, Wq, Wk, Wv, bq, bk, bv, outp);
}

// Round 8
// 81.521 us; speedup vs baseline: 2.5046x; 1.4525x over previous
//
#include <hip/hip_runtime.h>
#include <stdint.h>

#define B_ 32
#define S_ 512
#define D_ 768
#define H_ 12
#define DH_ 64

typedef __attribute__((ext_vector_type(8))) short bf16x8;
typedef __attribute__((ext_vector_type(4))) float f32x4;
typedef __attribute__((ext_vector_type(4))) short short4v;
typedef __attribute__((ext_vector_type(4))) unsigned int u32x4;

// ---- LDS layout (u16 units), pitch 72/136 => conflict-free b128 fragment reads
// Ws : [192][72] bf16  Wq rows 0-63, Wk 64-127, Wv 128-191   @ 0
// xs : [128][72] bf16  x chunk                               @ 13824
// Kc : [128][72] bf16  K chunk, e-cols sigma-permuted        @ 23040
// Vt : [64][136] bf16  V^T chunk, t-cols sigma-permuted      @ 32256
#define WP 72
#define VP 136
#define WS_U 0
#define XS_U 13824
#define KC_U 23040
#define VT_U 32256
#define SMEM_BYTES 81920  // 40960 u16, 2 blocks/CU

__device__ __forceinline__ unsigned short f2bf(float f) {
  uint32_t u = __builtin_bit_cast(uint32_t, f);
  return (unsigned short)((u + 0x7fffu + ((u >> 16) & 1u)) >> 16);  // RNE (prologue only)
}

// pack two f32 -> two bf16 (round half-up: same 0.5-ulp bound as RNE).
// 2x v_add + 1x v_perm_b32 = 3 VALU ops per pair.
__device__ __forceinline__ uint32_t pk2bf(float a, float b) {
  uint32_t ua = __builtin_bit_cast(uint32_t, a) + 0x8000u;
  uint32_t ub = __builtin_bit_cast(uint32_t, b) + 0x8000u;
  return __builtin_amdgcn_perm(ub, ua, 0x07060302u);  // {ub[31:16], ua[31:16]}
}

// sigma: value index v = 16*tile + r16 -> stored col so a contiguous 8-elem
// read at col8 = 32c + 8g yields k-order 32c + 16*(j>>2) + 4g + (j&3).
__device__ __forceinline__ int sigma(int tile, int r16) {
  return 32 * (tile >> 1) + 8 * (r16 >> 2) + 4 * (tile & 1) + (r16 & 3);
}

__device__ __forceinline__ bf16x8 ldfrag8(const unsigned short* p) {
  return *(const bf16x8*)p;  // single ds_read_b128
}

#define MFMA(a, b, c) __builtin_amdgcn_mfma_f32_16x16x32_bf16((a), (b), (c), 0, 0, 0)

extern "C" __global__ void __launch_bounds__(512, 2)
mhsa_mfma(const float* __restrict__ seq, const float* __restrict__ Wq,
          const float* __restrict__ Wk, const float* __restrict__ Wv,
          const float* __restrict__ bq, const float* __restrict__ bk,
          const float* __restrict__ bv, float* __restrict__ out)
{
  extern __shared__ unsigned short lds[];
  unsigned short* Ws = lds + WS_U;
  unsigned short* xs = lds + XS_U;
  unsigned short* Kc = lds + KC_U;
  unsigned short* Vt = lds + VT_U;

  const int tid = threadIdx.x;
  const int lane = tid & 63;
  const int w = tid >> 6;       // wave 0..7
  const int g = lane >> 4;      // lane quad-group 0..3
  const int r16 = lane & 15;
  const int bh = blockIdx.x;
  const int b = bh / H_;
  const int h = bh - b * H_;
  const int r0 = blockIdx.y * 256;  // this block's q-row base
  const int cb8 = 8 * g;            // contiguous fragment column base

  const float* seqh = seq + (size_t)b * (S_ * D_) + h * DH_;

  // ---- stage W fp32 -> bf16 LDS (rows padded to pitch 72; once, scalar RNE) ----
  #pragma unroll
  for (int i = 0; i < 24; ++i) {
    int idx = tid + i * 512;
    int row = idx >> 6, col = idx & 63;
    const float* src = (idx < 4096) ? (Wq + h * 4096 + idx)
                     : (idx < 8192) ? (Wk + h * 4096 + (idx - 4096))
                                    : (Wv + h * 4096 + (idx - 8192));
    Ws[row * WP + col] = f2bf(*src);
  }
  __syncthreads();

  // ---- persistent W fragments (contiguous-8 k-order; consistent both sides) ----
  bf16x8 wkB[4][2];
  #pragma unroll
  for (int e4 = 0; e4 < 4; ++e4)
    #pragma unroll
    for (int ec = 0; ec < 2; ++ec)
      wkB[e4][ec] = ldfrag8(Ws + (64 + 16 * e4 + r16) * WP + 32 * ec + cb8);
  const int ev = w & 3;   // V^T e-tile owned by this wave
  const int th = w >> 2;  // V^T t-half
  bf16x8 wvA[2];
  #pragma unroll
  for (int ec = 0; ec < 2; ++ec)
    wvA[ec] = ldfrag8(Ws + (128 + 16 * ev + r16) * WP + 32 * ec + cb8);

  float bk_l[4], bv_l[4];
  #pragma unroll
  for (int e4 = 0; e4 < 4; ++e4) bk_l[e4] = bk[h * 64 + 16 * e4 + r16];
  #pragma unroll
  for (int rr = 0; rr < 4; ++rr) bv_l[rr] = bv[h * 64 + 16 * ev + 4 * g + rr];

  // ---- pre-phase: Q^T via MFMA -> qB register fragments ----
  bf16x8 qB[2][2];  // [m-tile][e-chunk]; elem j: e = 32ec2+16(j>>2)+4g+(j&3)
  for (int cq = 0; cq < 2; ++cq) {
    __syncthreads();
    #pragma unroll
    for (int i = 0; i < 4; ++i) {
      int idx = tid + i * 512;
      int row = idx >> 4, c4 = (idx & 15) << 2;
      const float4 xv = *(const float4*)(seqh + (size_t)(r0 + cq * 128 + row) * D_ + c4);
      uint2 p;
      p.x = pk2bf(xv.x, xv.y);
      p.y = pk2bf(xv.z, xv.w);
      *(uint2*)(xs + row * WP + c4) = p;
    }
    __syncthreads();
    if (th == cq) {
      const int lr = 32 * ev;  // wave's rows within this 128-chunk
      #pragma unroll
      for (int mt = 0; mt < 2; ++mt) {
        bf16x8 xB[2];
        #pragma unroll
        for (int ec = 0; ec < 2; ++ec)
          xB[ec] = ldfrag8(xs + (lr + 16 * mt + r16) * WP + 32 * ec + cb8);
        f32x4 qt[4];
        #pragma unroll
        for (int e4 = 0; e4 < 4; ++e4) {
          f32x4 acc = {0.f, 0.f, 0.f, 0.f};
          #pragma unroll
          for (int ec = 0; ec < 2; ++ec)
            acc = MFMA(ldfrag8(Ws + (16 * e4 + r16) * WP + 32 * ec + cb8), xB[ec], acc);
          qt[e4] = acc;
        }
        #pragma unroll
        for (int ec2 = 0; ec2 < 2; ++ec2) {
          const int eA = 2 * ec2, eB = 2 * ec2 + 1;
          u32x4 t;
          t[0] = pk2bf(qt[eA][0] + bq[h * 64 + 16 * eA + 4 * g + 0],
                       qt[eA][1] + bq[h * 64 + 16 * eA + 4 * g + 1]);
          t[1] = pk2bf(qt[eA][2] + bq[h * 64 + 16 * eA + 4 * g + 2],
                       qt[eA][3] + bq[h * 64 + 16 * eA + 4 * g + 3]);
          t[2] = pk2bf(qt[eB][0] + bq[h * 64 + 16 * eB + 4 * g + 0],
                       qt[eB][1] + bq[h * 64 + 16 * eB + 4 * g + 1]);
          t[3] = pk2bf(qt[eB][2] + bq[h * 64 + 16 * eB + 4 * g + 2],
                       qt[eB][3] + bq[h * 64 + 16 * eB + 4 * g + 3]);
          qB[mt][ec2] = __builtin_bit_cast(bf16x8, t);
        }
      }
    }
  }

  // ---- main flash loop over 4 t-chunks of 128 ----
  f32x4 O[2][4];
  #pragma unroll
  for (int mt = 0; mt < 2; ++mt)
    #pragma unroll
    for (int e4 = 0; e4 < 4; ++e4) O[mt][e4] = {0.f, 0.f, 0.f, 0.f};
  float m_st[2] = {-1e30f, -1e30f}, l_st[2] = {0.f, 0.f};
  const int m0w = w * 32;

  for (int c = 0; c < 4; ++c) {
    __syncthreads();  // prev chunk's consumers done
    #pragma unroll
    for (int i = 0; i < 4; ++i) {
      int idx = tid + i * 512;
      int row = idx >> 4, c4 = (idx & 15) << 2;
      const float4 xv = *(const float4*)(seqh + (size_t)(c * 128 + row) * D_ + c4);
      uint2 p;
      p.x = pk2bf(xv.x, xv.y);
      p.y = pk2bf(xv.z, xv.w);
      *(uint2*)(xs + row * WP + c4) = p;
    }
    __syncthreads();

    // K-proj: wave w owns t-tile w; store e-cols sigma-permuted
    {
      bf16x8 aX[2];
      #pragma unroll
      for (int ec = 0; ec < 2; ++ec)
        aX[ec] = ldfrag8(xs + (w * 16 + r16) * WP + 32 * ec + cb8);
      #pragma unroll
      for (int e4 = 0; e4 < 4; ++e4) {
        f32x4 acc = {0.f, 0.f, 0.f, 0.f};
        #pragma unroll
        for (int ec = 0; ec < 2; ++ec) acc = MFMA(aX[ec], wkB[e4][ec], acc);
        const float bkv = bk_l[e4];
        const int rb = w * 16 + 4 * g;
        const int cs = sigma(e4, r16);
        uint32_t k01 = pk2bf(acc[0] + bkv, acc[1] + bkv);
        uint32_t k23 = pk2bf(acc[2] + bkv, acc[3] + bkv);
        Kc[(rb + 0) * WP + cs] = (unsigned short)k01;
        Kc[(rb + 1) * WP + cs] = (unsigned short)(k01 >> 16);
        Kc[(rb + 2) * WP + cs] = (unsigned short)k23;
        Kc[(rb + 3) * WP + cs] = (unsigned short)(k23 >> 16);
      }
    }
    // V^T-proj: wave w owns e-tile ev, t-tiles th*4..th*4+3; t-cols sigma-permuted
    #pragma unroll
    for (int ttl = 0; ttl < 4; ++ttl) {
      int tt = th * 4 + ttl;
      bf16x8 xB[2];
      #pragma unroll
      for (int ec = 0; ec < 2; ++ec)
        xB[ec] = ldfrag8(xs + (tt * 16 + r16) * WP + 32 * ec + cb8);
      f32x4 acc = {0.f, 0.f, 0.f, 0.f};
      #pragma unroll
      for (int ec = 0; ec < 2; ++ec) acc = MFMA(wvA[ec], xB[ec], acc);
      const int rb = 16 * ev + 4 * g;
      const int cs = sigma(tt, r16);
      uint32_t v01 = pk2bf(acc[0] + bv_l[0], acc[1] + bv_l[1]);
      uint32_t v23 = pk2bf(acc[2] + bv_l[2], acc[3] + bv_l[3]);
      Vt[(rb + 0) * VP + cs] = (unsigned short)v01;
      Vt[(rb + 1) * VP + cs] = (unsigned short)(v01 >> 16);
      Vt[(rb + 2) * VP + cs] = (unsigned short)v23;
      Vt[(rb + 3) * VP + cs] = (unsigned short)(v23 >> 16);
    }
    __syncthreads();

    // S^T + online softmax (defer-max THR=8) + PV
    bf16x8 pA[4][2];
    #pragma unroll
    for (int mt = 0; mt < 2; ++mt) {
      f32x4 st[8];
      #pragma unroll
      for (int tt = 0; tt < 8; ++tt) {
        bf16x8 aK[2];
        #pragma unroll
        for (int ec = 0; ec < 2; ++ec)
          aK[ec] = ldfrag8(Kc + (tt * 16 + r16) * WP + 32 * ec + cb8);
        f32x4 acc = {0.f, 0.f, 0.f, 0.f};
        #pragma unroll
        for (int ec = 0; ec < 2; ++ec) acc = MFMA(aK[ec], qB[mt][ec], acc);
        st[tt] = acc;
      }
      float mx = st[0][0];
      #pragma unroll
      for (int tt = 0; tt < 8; ++tt)
        #pragma unroll
        for (int rr = 0; rr < 4; ++rr) mx = fmaxf(mx, st[tt][rr]);
      mx = fmaxf(mx, __shfl_xor(mx, 16, 64));
      mx = fmaxf(mx, __shfl_xor(mx, 32, 64));
      // T13: only rescale when some row's max grew by > 8 (P bounded by e^8)
      if (!__all(mx <= m_st[mt] + 8.0f)) {
        float mn = fmaxf(m_st[mt], mx);
        float al = __expf(m_st[mt] - mn);
        m_st[mt] = mn;
        float af[4];
        #pragma unroll
        for (int rr = 0; rr < 4; ++rr) af[rr] = __shfl(al, 4 * g + rr, 64);
        #pragma unroll
        for (int e4 = 0; e4 < 4; ++e4)
          #pragma unroll
          for (int rr = 0; rr < 4; ++rr) O[mt][e4][rr] *= af[rr];
        l_st[mt] *= al;
      }
      const float mcur = m_st[mt];
      float sum = 0.f;
      #pragma unroll
      for (int tt = 0; tt < 8; ++tt)
        #pragma unroll
        for (int rr = 0; rr < 4; ++rr) {
          float pv = __expf(st[tt][rr] - mcur);
          st[tt][rr] = pv;
          sum += pv;
        }
      sum += __shfl_xor(sum, 16, 64);
      sum += __shfl_xor(sum, 32, 64);
      l_st[mt] += sum;
      #pragma unroll
      for (int u = 0; u < 4; ++u) {
        u32x4 t;
        t[0] = pk2bf(st[2 * u][0], st[2 * u][1]);
        t[1] = pk2bf(st[2 * u][2], st[2 * u][3]);
        t[2] = pk2bf(st[2 * u + 1][0], st[2 * u + 1][1]);
        t[3] = pk2bf(st[2 * u + 1][2], st[2 * u + 1][3]);
        pA[u][mt] = __builtin_bit_cast(bf16x8, t);
      }
    }
    #pragma unroll
    for (int u = 0; u < 4; ++u) {
      bf16x8 vB[4];
      #pragma unroll
      for (int e4 = 0; e4 < 4; ++e4)
        vB[e4] = ldfrag8(Vt + (16 * e4 + r16) * VP + 32 * u + cb8);
      #pragma unroll
      for (int mt = 0; mt < 2; ++mt)
        #pragma unroll
        for (int e4 = 0; e4 < 4; ++e4)
          O[mt][e4] = MFMA(pA[u][mt], vB[e4], O[mt][e4]);
    }
  }

  // ---- epilogue: normalize + store ----
  #pragma unroll
  for (int mt = 0; mt < 2; ++mt) {
    float inv[4];
    #pragma unroll
    for (int rr = 0; rr < 4; ++rr) inv[rr] = 1.0f / __shfl(l_st[mt], 4 * g + rr, 64);
    #pragma unroll
    for (int e4 = 0; e4 < 4; ++e4)
      #pragma unroll
      for (int rr = 0; rr < 4; ++rr)
        out[(size_t)(b * S_ + r0 + m0w + 16 * mt + 4 * g + rr) * D_ + h * DH_ + 16 * e4 + r16] =
            O[mt][e4][rr] * inv[rr];
  }
}

extern "C" void kernel_launch(void* const* d_in, const int* in_sizes, int n_in,
                              void* d_out, int out_size, void* d_ws, size_t ws_size,
                              hipStream_t stream) {
  const float* seq = (const float*)d_in[0];
  const float* Wq  = (const float*)d_in[1];
  const float* Wk  = (const float*)d_in[2];
  const float* Wv  = (const float*)d_in[3];
  const float* bq  = (const float*)d_in[4];
  const float* bk  = (const float*)d_in[5];
  const float* bv  = (const float*)d_in[6];
  float* outp = (float*)d_out;

  hipFuncSetAttribute((const void*)mhsa_mfma,
                      hipFuncAttributeMaxDynamicSharedMemorySize, SMEM_BYTES);
  dim3 grid(B_ * H_, 2);
  mhsa_mfma<<<grid, 512, SMEM_BYTES, stream>>>(seq, Wq, Wk, Wv, bq, bk, bv, outp);
}